// Round 8
// baseline (661.547 us; speedup 1.0000x reference)
//
#include <hip/hip_runtime.h>
#include <hip/hip_bf16.h>
#include <cstdint>

typedef float f32x4 __attribute__((ext_vector_type(4)));
typedef short short8v __attribute__((ext_vector_type(8)));

#define ATT 256
#define D_IN 512
#define TR 32                     // rows per tile = 8 samples

static __device__ __forceinline__ unsigned short f2bf(float x) {
    return __builtin_bit_cast(unsigned short, __float2bfloat16(x));
}
static __device__ __forceinline__ float bf2f(unsigned short us) {
    return __builtin_bit_cast(float, (uint32_t)us << 16);
}
// exact identity tanh(x) = 1 - 2/(1+e^{2x}); saturates cleanly at +-1
static __device__ __forceinline__ float fast_tanhf(float x) {
    return 1.0f - 2.0f / (1.0f + __expf(2.0f * x));
}

// ---------------------------------------------------------------------------
// Pre-kernel: W [512][256] fp32 -> bf16 in B-fragment order:
//   o = ((ks*16 + nt)*64 + lane)*8 + j  holds  W[ks*32 + hi*8 + j][nt*16 + lo]
// ---------------------------------------------------------------------------
__global__ void wconv_kernel(const float* __restrict__ W, unsigned short* __restrict__ Wf) {
    int o = blockIdx.x * 256 + threadIdx.x;      // 0 .. 131071
    int j  = o & 7;
    int ln = (o >> 3) & 63;
    int nt = (o >> 9) & 15;
    int ks = o >> 13;
    int hi = ln >> 4, lo = ln & 15;
    Wf[o] = f2bf(W[(ks * 32 + hi * 8 + j) * ATT + nt * 16 + lo]);
}

// ---------------------------------------------------------------------------
// Main kernel: 256 threads = 4 waves; tile = 32 rows (8 samples).
// Wave w computes all 32 rows x cols [w*64, w*64+64) (4 nt): acc = 32 VGPR.
// B-fragments streamed from L2 (Wf 256 KB stays L2-hot; X loads are
// nontemporal so they can't evict it). X tile staged bf16 in LDS (32 KB,
// single buffer; 4 blocks/CU stagger the stage phases).
//
// LDS chunk layout (chunk = 16B granule index):
//   data (row,k): ks=k>>5, rh=row>>4, m=(k>>3)&3, lane_f=(row&15)+m*16
//   chunk = (ks*2+rh)*64 + (lane_f ^ (ks&7))
//   - staging writes chunks linearly (tid + it*256)  -> optimal ds_write
//   - A-frag read:  off = (ks*2+rh)*1024 + (lane*16 ^ ((ks&7)<<4))  -> optimal
//   - epilogue read: bank-quad = (row&7) ^ ((lane>>2)&7)            -> uniform
// ---------------------------------------------------------------------------
__global__ __launch_bounds__(256, 4) void att_main(
    const float* __restrict__ X, const unsigned short* __restrict__ Wf,
    const float* __restrict__ bb, const float* __restrict__ uu,
    float* __restrict__ out, float* __restrict__ alph,
    int ntiles, int tpb)
{
    __shared__ __align__(16) unsigned short Xs[TR * D_IN];   // 32 KB
    __shared__ __align__(16) float vured[4][8][4];           // 512 B
    __shared__ float alsh[32];

    const int tid  = threadIdx.x;
    const int wid  = tid >> 6;                   // 0..3
    const int lane = tid & 63;
    const int lo   = lane & 15;
    const int hi   = lane >> 4;
    const int lane16 = lane * 16;

    const int tile0 = blockIdx.x * tpb;
    if (tile0 >= ntiles) return;

    // b,u for this wave's 4 column-tiles
    float bv[4], uv[4];
    #pragma unroll
    for (int n = 0; n < 4; ++n) {
        int c = wid * 64 + n * 16 + lo;
        bv[n] = bb[c];
        uv[n] = uu[c];
    }

    const short8v* Wp = (const short8v*)Wf;

    for (int i = 0; i < tpb; ++i) {
        const int tile = tile0 + i;
        if (tile >= ntiles) break;

        // ---- stage phase: 32 rows x 512 fp32 -> bf16 LDS (linear chunks) ----
        {
            const float* Xg = X + (int64_t)tile * (TR * D_IN);
            #pragma unroll
            for (int it = 0; it < 8; ++it) {
                int c = tid + it * 256;          // chunk 0..2047
                int frag = c >> 6, q = c & 63;
                int ks = frag >> 1, rh = frag & 1;
                int lf = q ^ (ks & 7);
                int row = rh * 16 + (lf & 15);
                int c8 = ks * 4 + (lf >> 4);
                const f32x4* src = (const f32x4*)(Xg + row * D_IN + c8 * 8);
                f32x4 va = __builtin_nontemporal_load(src);
                f32x4 vb = __builtin_nontemporal_load(src + 1);
                short8v pk;
                pk[0] = (short)f2bf(va.x); pk[1] = (short)f2bf(va.y);
                pk[2] = (short)f2bf(va.z); pk[3] = (short)f2bf(va.w);
                pk[4] = (short)f2bf(vb.x); pk[5] = (short)f2bf(vb.y);
                pk[6] = (short)f2bf(vb.z); pk[7] = (short)f2bf(vb.w);
                *(short8v*)((char*)Xs + c * 16) = pk;
            }
        }
        __syncthreads();

        // ---- k-loop: B-frags from L2, A-frags from LDS ----
        f32x4 acc[2][4];
        #pragma unroll
        for (int rh = 0; rh < 2; ++rh)
            #pragma unroll
            for (int n = 0; n < 4; ++n)
                acc[rh][n] = (f32x4){0.f, 0.f, 0.f, 0.f};

        #pragma unroll
        for (int ks = 0; ks < 16; ++ks) {
            short8v bfr[4];
            #pragma unroll
            for (int n = 0; n < 4; ++n)
                bfr[n] = Wp[(ks * 16 + wid * 4 + n) * 64 + lane];
            #pragma unroll
            for (int rh = 0; rh < 2; ++rh) {
                short8v a = *(const short8v*)((const char*)Xs +
                        (ks * 2 + rh) * 1024 + (lane16 ^ ((ks & 7) << 4)));
                #pragma unroll
                for (int n = 0; n < 4; ++n)
                    acc[rh][n] = __builtin_amdgcn_mfma_f32_16x16x32_bf16(
                                     a, bfr[n], acc[rh][n], 0, 0, 0);
            }
        }

        // ---- epilogue 1: tanh + u-dot partials, butterfly over 16 col-lanes ----
        // C/D layout: col = wid*64 + n*16 + lo, row = rh*16 + hi*4 + r
        float p[2][4];
        #pragma unroll
        for (int rh = 0; rh < 2; ++rh)
            #pragma unroll
            for (int r = 0; r < 4; ++r) {
                float s = 0.f;
                #pragma unroll
                for (int n = 0; n < 4; ++n)
                    s += fast_tanhf(acc[rh][n][r] + bv[n]) * uv[n];
                p[rh][r] = s;
            }
        #pragma unroll
        for (int m = 1; m < 16; m <<= 1)
            #pragma unroll
            for (int rh = 0; rh < 2; ++rh)
                #pragma unroll
                for (int r = 0; r < 4; ++r)
                    p[rh][r] += __shfl_xor(p[rh][r], m, 64);
        if (lo == 0) {                           // lanes 0,16,32,48 (hi = 0..3)
            #pragma unroll
            for (int rh = 0; rh < 2; ++rh) {
                f32x4 v4 = {p[rh][0], p[rh][1], p[rh][2], p[rh][3]};
                *(f32x4*)&vured[wid][rh * 4 + hi][0] = v4;   // sample = rh*4+hi
            }
        }
        __syncthreads();

        // ---- softmax over t (4) per sample (8), cross-wave sum ----
        if (tid < 32) {
            int s = tid >> 2, t = tid & 3;
            float v = vured[0][s][t] + vured[1][s][t] + vured[2][s][t] + vured[3][s][t];
            float mx = fmaxf(v, __shfl_xor(v, 1, 64));
            mx = fmaxf(mx, __shfl_xor(mx, 2, 64));
            float e = __expf(v - mx);
            float sm = e + __shfl_xor(e, 1, 64);
            sm += __shfl_xor(sm, 2, 64);
            float av = e / sm;
            alsh[tid] = av;
            alph[(int64_t)tile * 32 + tid] = av;
        }
        __syncthreads();

        // ---- out: wave w handles samples {2w, 2w+1}; lane owns d = lane*8..+8 ----
        #pragma unroll
        for (int ss = 0; ss < 2; ++ss) {
            int s = wid * 2 + ss;
            float a0 = alsh[s * 4 + 0], a1 = alsh[s * 4 + 1];
            float a2 = alsh[s * 4 + 2], a3 = alsh[s * 4 + 3];
            float o[8];
            #pragma unroll
            for (int e = 0; e < 8; ++e) o[e] = 0.f;
            #pragma unroll
            for (int r = 0; r < 4; ++r) {
                int row = s * 4 + r;
                int rh = row >> 4, r15 = row & 15;
                int off = ((lane >> 2) * 2 + rh) * 1024 +
                          (((r15 + (lane & 3) * 16) ^ ((lane >> 2) & 7)) * 16);
                short8v xq = *(const short8v*)((const char*)Xs + off);
                float ar = (r == 0) ? a0 : (r == 1) ? a1 : (r == 2) ? a2 : a3;
                #pragma unroll
                for (int e = 0; e < 8; ++e)
                    o[e] += ar * bf2f((unsigned short)xq[e]);
            }
            float* outp = out + ((int64_t)tile * 8 + s) * D_IN + lane * 8;
            f32x4 o4a = {o[0], o[1], o[2], o[3]};
            f32x4 o4b = {o[4], o[5], o[6], o[7]};
            __builtin_nontemporal_store(o4a, (f32x4*)outp);
            __builtin_nontemporal_store(o4b, (f32x4*)(outp + 4));
        }
        __syncthreads();   // Xs free for next tile's stage
    }
}

// ---------------------------------------------------------------------------
// Fallback (generality): plain fp32, 1 block per sample.
// ---------------------------------------------------------------------------
__global__ void att_fallback(const float* __restrict__ X, const float* __restrict__ W,
                             const float* __restrict__ bb, const float* __restrict__ uu,
                             float* __restrict__ out, float* __restrict__ alph)
{
    const int s = blockIdx.x;
    const int tid = threadIdx.x;                   // 256 threads
    __shared__ float Xsf[2048];
    __shared__ float red[4][4];
    __shared__ float alshf[4];
    for (int i = tid; i < 2048; i += 256) Xsf[i] = X[(size_t)s * 2048 + i];
    __syncthreads();
    float vus[4];
    const int a = tid;
    for (int t = 0; t < 4; ++t) {
        float acc = bb[a];
        for (int d = 0; d < 512; ++d) acc += Xsf[t * 512 + d] * W[d * 256 + a];
        vus[t] = tanhf(acc) * uu[a];
    }
    const int wid = tid >> 6, lane = tid & 63;
    for (int t = 0; t < 4; ++t) {
        float v = vus[t];
        for (int m = 1; m < 64; m <<= 1) v += __shfl_xor(v, m, 64);
        if (lane == 0) red[t][wid] = v;
    }
    __syncthreads();
    if (tid == 0) {
        float vv[4];
        for (int t = 0; t < 4; ++t) vv[t] = red[t][0] + red[t][1] + red[t][2] + red[t][3];
        float mx = fmaxf(fmaxf(vv[0], vv[1]), fmaxf(vv[2], vv[3]));
        float e[4], ssum = 0.f;
        for (int t = 0; t < 4; ++t) { e[t] = expf(vv[t] - mx); ssum += e[t]; }
        for (int t = 0; t < 4; ++t) {
            float av = e[t] / ssum;
            alshf[t] = av;
            alph[(size_t)s * 4 + t] = av;
        }
    }
    __syncthreads();
    for (int d = tid; d < 512; d += 256) {
        float o = 0.f;
        for (int t = 0; t < 4; ++t) o += alshf[t] * Xsf[t * 512 + d];
        out[(size_t)s * 512 + d] = o;
    }
}

// ---------------------------------------------------------------------------
extern "C" void kernel_launch(void* const* d_in, const int* in_sizes, int n_in,
                              void* d_out, int out_size, void* d_ws, size_t ws_size,
                              hipStream_t stream) {
    const float* X = (const float*)d_in[0];
    const float* W = (const float*)d_in[1];
    const float* b = (const float*)d_in[2];
    const float* u = (const float*)d_in[3];
    float* out = (float*)d_out;
    const int N = in_sizes[0] / (4 * D_IN);        // samples
    float* alph = out + (size_t)N * D_IN;

    if (ws_size >= (size_t)D_IN * ATT * sizeof(unsigned short) && (N % 8) == 0) {
        unsigned short* Wf = (unsigned short*)d_ws;
        wconv_kernel<<<(D_IN * ATT) / 256, 256, 0, stream>>>(W, Wf);
        const int ntiles = (N * 4) / TR;           // 32-row tiles
        const int grid = ntiles < 1024 ? ntiles : 1024;
        const int tpb = (ntiles + grid - 1) / grid;
        att_main<<<grid, 256, 0, stream>>>(X, Wf, b, u, out, alph, ntiles, tpb);
    } else {
        att_fallback<<<N, 256, 0, stream>>>(X, W, b, u, out, alph);
    }
}